// Round 20
// baseline (327.837 us; speedup 1.0000x reference)
//
#include <hip/hip_runtime.h>
#include <stdint.h>

typedef unsigned short u16;
typedef __attribute__((ext_vector_type(8))) short  s8b;   // 8 bf16 (4 VGPRs)
typedef __attribute__((ext_vector_type(4))) float  f32x4;

#define S_LEN   2048
#define NHEAD   16
#define HD      128
#define DM      2048
#define NB      2
#define NPLANE  (NB*NHEAD)          // 32
#define ROWS    (NB*S_LEN)          // 4096 = M for all GEMMs
#define PLANE_ELEMS (S_LEN*HD)      // 262144
#define ATT_SCALE 0.08838834764831845f   // 1/sqrt(128)
#define LOG2E     1.4426950408889634f

__device__ __forceinline__ float bf2f(u16 u){
  union { unsigned u; float f; } x; x.u = ((unsigned)u) << 16; return x.f;
}
__device__ __forceinline__ u16 f2bf(float f){
  union { float f; unsigned u; } x; x.f = f;
  unsigned r = x.u + 0x7FFFu + ((x.u >> 16) & 1u);   // RNE
  return (u16)(r >> 16);
}
__device__ __forceinline__ unsigned cvtpk(float lo, float hi){
  unsigned r;
  asm("v_cvt_pk_bf16_f32 %0, %1, %2" : "=v"(r) : "v"(lo), "v"(hi));
  return r;
}

typedef const __attribute__((address_space(1))) unsigned int* gas1;
typedef __attribute__((address_space(3))) unsigned int* las3;
__device__ __forceinline__ void gload16(const void* g, void* l){
  __builtin_amdgcn_global_load_lds((gas1)g, (las3)l, 16, 0, 0);
}

__device__ __forceinline__ f32x4 mfma16(s8b a, s8b b, f32x4 c){
  return __builtin_amdgcn_mfma_f32_16x16x32_bf16(a, b, c, 0, 0, 0);
}

// ---------------- elementwise f32 -> bf16, 3 tensors in one launch ----------------
__global__ __launch_bounds__(256) void cvt4x3(const float4* __restrict__ a,
                                              const float4* __restrict__ b,
                                              const float4* __restrict__ c,
                                              uint2* __restrict__ oa,
                                              uint2* __restrict__ ob,
                                              uint2* __restrict__ oc, int n4){
  int i = blockIdx.x*256 + threadIdx.x;
  if (i >= n4) return;
  const float4* src = (blockIdx.y == 0) ? a : (blockIdx.y == 1) ? b : c;
  uint2*       dst  = (blockIdx.y == 0) ? oa : (blockIdx.y == 1) ? ob : oc;
  float4 v = src[i];
  uint2 o;
  o.x = (unsigned)f2bf(v.x) | ((unsigned)f2bf(v.y) << 16);
  o.y = (unsigned)f2bf(v.z) | ((unsigned)f2bf(v.w) << 16);
  dst[i] = o;
}

// ---------------- all 4 weight transposes in ONE launch (plain B^T layout) ----------------
__global__ __launch_bounds__(256) void transpose_all(const float* __restrict__ WQ,
                                                     const float* __restrict__ WK,
                                                     const float* __restrict__ WV,
                                                     const float* __restrict__ WO,
                                                     u16* __restrict__ WqT,
                                                     u16* __restrict__ WkT,
                                                     u16* __restrict__ WvT,
                                                     u16* __restrict__ WoT){
  __shared__ float tile[32][33];
  int u = blockIdx.x;
  int mat = u >> 12, rem = u & 4095;
  const float* in; u16* out; int R, C, outStride, z, r0, c0;
  if (mat == 0){
    in = WO; out = WoT; R = 2048; C = 2048; outStride = 2048; z = 0;
    r0 = (rem & 63)*32; c0 = (rem >> 6)*32;
  } else {
    in  = (mat == 1) ? WQ  : (mat == 2) ? WK  : WV;
    out = (mat == 1) ? WqT : (mat == 2) ? WkT : WvT;
    R = 2048; C = 128; outStride = 2048;
    z  = rem >> 8;                 // head 0..15
    r0 = (rem & 63)*32; c0 = ((rem >> 6) & 3)*32;
  }
  const float* inz = in + (size_t)z * R * C;
  u16* outz = out + (size_t)z * C * outStride;
  int tx = threadIdx.x & 31, ty = threadIdx.x >> 5;   // (32,8)
  #pragma unroll
  for (int i=0;i<4;i++)
    tile[ty*4+i][tx] = inz[(size_t)(r0+ty*4+i)*C + c0 + tx];
  __syncthreads();
  #pragma unroll
  for (int i=0;i<4;i++)
    outz[(size_t)(c0+ty*4+i)*outStride + r0 + tx] = f2bf(tile[tx][ty*4+i]);
}

// ---------------- RoPE table (f32) ----------------
__global__ __launch_bounds__(256) void rope_tab(float* __restrict__ ctab,
                                                float* __restrict__ stab){
  int i = blockIdx.x*256 + threadIdx.x;   // S_LEN*64
  int p = i >> 6, j = i & 63;
  float freq = exp2f(-(float)j * (13.287712379549449f/64.0f));  // 10000^(-j/64)
  float a = (float)p * freq;
  ctab[i] = cosf(a);
  stab[i] = sinf(a);
}

// ---------------- GEMM core (round-12 proven ring-6, counted vmcnt(9)) -------------------
// 256x128 tile, BK=64, 8 waves (4Mx2N), ring-6 half-slots (144KB), 2 phases x 16 MFMA,
// 2 barriers/K-tile, (row&7)<<4 swizzle both-sides, XCD swizzle.
// mode 0: bf16 plain (B,H,S,F) | mode 1: V fragment-linear | mode 2: f32+bias
__device__ __forceinline__ void gemm_core(u16* lds,
                                          const u16* __restrict__ A,
                                          const u16* __restrict__ BT,
                                          const float* __restrict__ bias,
                                          void* __restrict__ out, int mode){
  const int K = 2048;
  const int NT = 32;                       // K/64
  const int t = threadIdx.x, w = t >> 6, l = t & 63;
  const int lr = l & 15, lg = l >> 4;
  const int wr = w >> 1, wc = w & 1;       // 4M x 2N waves, 64x64 output each
  int bid = blockIdx.x;
  int swz = (bid & 7)*32 + (bid >> 3);     // 256 % 8 == 0, bijective
  const int M0 = (swz >> 4) * 256, N0 = (swz & 15) * 128;

  f32x4 acc[4][4];
  #pragma unroll
  for (int i=0;i<4;i++)
    #pragma unroll
    for (int j=0;j<4;j++) acc[i][j] = f32x4{0.f,0.f,0.f,0.f};

  auto stageH = [&](int ttu, int h){
    int slot = (2*ttu + h) % 6;
    int tt   = ttu & 31;
    char* base = (char*)&lds[slot*12288];
    #pragma unroll
    for (int j=0;j<2;j++){                       // A-half: 128 rows x 128B
      int d = w*2048 + j*1024 + l*16;
      int row = d >> 7;                          // 0..127
      int koff = ((l&7)*16) ^ ((row&7)<<4);
      gload16((const char*)A + ((size_t)(M0 + h*128 + row)*K + tt*64)*2 + koff,
              base + w*2048 + j*1024);
    }
    {                                            // B-half: 64 rows x 128B
      int d = w*1024 + l*16;
      int row = d >> 7;                          // 0..63
      int koff = ((l&7)*16) ^ ((row&7)<<4);
      gload16((const char*)BT + ((size_t)(N0 + h*64 + row)*K + tt*64)*2 + koff,
              base + 16384 + w*1024);
    }
  };

  stageH(0,0); stageH(0,1); stageH(1,0); stageH(1,1);

  for (int kt=0; kt<NT; kt++){
    const char* Ab = (const char*)&lds[((2*kt + (wr>>1)) % 6)*12288];
    const char* Bb = (const char*)&lds[((2*kt + wc) % 6)*12288] + 16384;

    // ---- P0: issue H(t+2,0); counted wait; barrier; af + bf(nj0,1); 16 MFMA ----
    stageH(kt+2, 0);
    asm volatile("s_waitcnt vmcnt(9)" ::: "memory");   // tile kt fully landed
    __builtin_amdgcn_s_barrier();
    __builtin_amdgcn_sched_barrier(0);

    s8b af[4][2];
    #pragma unroll
    for (int mi=0;mi<4;mi++)
      #pragma unroll
      for (int kc=0;kc<2;kc++){
        int rA = (wr&1)*64 + mi*16 + lr;
        af[mi][kc] = *(const s8b*)(Ab + rA*128 + ((kc*64 + lg*16) ^ ((rA&7)<<4)));
      }
    {
      s8b bf[2][2];
      #pragma unroll
      for (int nj=0;nj<2;nj++){
        int rB = nj*16 + lr;
        bf[nj][0] = *(const s8b*)(Bb + rB*128 + ((0*64 + lg*16) ^ ((rB&7)<<4)));
        bf[nj][1] = *(const s8b*)(Bb + rB*128 + ((1*64 + lg*16) ^ ((rB&7)<<4)));
      }
      __builtin_amdgcn_s_setprio(1);
      #pragma unroll
      for (int mi=0;mi<4;mi++)
        #pragma unroll
        for (int nj=0;nj<2;nj++){
          acc[mi][nj] = mfma16(af[mi][0], bf[nj][0], acc[mi][nj]);
          acc[mi][nj] = mfma16(af[mi][1], bf[nj][1], acc[mi][nj]);
        }
      __builtin_amdgcn_s_setprio(0);
    }
    // ---- P1: issue H(t+2,1); bf(nj2,3); 16 MFMA; end barrier ----
    stageH(kt+2, 1);
    {
      s8b bf[2][2];
      #pragma unroll
      for (int nj=0;nj<2;nj++){
        int rB = (nj+2)*16 + lr;
        bf[nj][0] = *(const s8b*)(Bb + rB*128 + ((0*64 + lg*16) ^ ((rB&7)<<4)));
        bf[nj][1] = *(const s8b*)(Bb + rB*128 + ((1*64 + lg*16) ^ ((rB&7)<<4)));
      }
      __builtin_amdgcn_s_setprio(1);
      #pragma unroll
      for (int mi=0;mi<4;mi++)
        #pragma unroll
        for (int nj=0;nj<2;nj++){
          acc[mi][nj+2] = mfma16(af[mi][0], bf[nj][0], acc[mi][nj+2]);
          acc[mi][nj+2] = mfma16(af[mi][1], bf[nj][1], acc[mi][nj+2]);
        }
      __builtin_amdgcn_s_setprio(0);
    }
    __builtin_amdgcn_sched_barrier(0);
    __builtin_amdgcn_s_barrier();
    __builtin_amdgcn_sched_barrier(0);
  }
  asm volatile("s_waitcnt vmcnt(0)" ::: "memory");   // drain wrap-stages

  // epilogue: D layout col=lane&15, row=(lane>>4)*4+reg
  #pragma unroll
  for (int mi=0;mi<4;mi++){
    int growb = M0 + wr*64 + mi*16 + lg*4;
    #pragma unroll
    for (int nj=0;nj<4;nj++){
      int gcol = N0 + wc*64 + nj*16 + lr;
      float bv = bias[gcol];
      #pragma unroll
      for (int r=0;r<4;r++){
        int grow = growb + r;
        float v = acc[mi][nj][r] + bv;
        if (mode == 2){
          ((float*)out)[(size_t)grow*2048 + gcol] = v;
        } else {
          int b = grow >> 11, p = grow & 2047;
          int h = gcol >> 7,  f = gcol & 127;
          if (mode == 0){
            ((u16*)out)[(((size_t)(b*NHEAD+h))*S_LEN + p)*HD + f] = f2bf(v);
          } else {
            // V fragment-linear: 16 frags x 1KB per kv-tile; sigma-permute folded in.
            size_t base = ((size_t)(b*NHEAD+h)*PLANE_ELEMS)*2 + (size_t)(p>>6)*16384;
            int p6 = p & 63;
            int q_ = ((p6&12)<<1) | (p6&3) | ((p6&16)>>2);
            int kvp = (p6 & 32) | q_;
            int kc = kvp >> 5, lgv = (kvp >> 3) & 3, jv = kvp & 7;
            int off = (kc*8 + (f>>4))*1024 + (lgv*16 + (f&15))*16 + jv*2;
            *(u16*)((char*)out + base + off) = f2bf(v);
          }
        }
      }
    }
  }
}

// merged QKV launch: blockIdx.y selects {q,k,v}
__global__ __launch_bounds__(512) void gemm_qkv(const u16* __restrict__ Aq,
                                                const u16* __restrict__ Ak,
                                                const u16* __restrict__ Av,
                                                const u16* __restrict__ Bq,
                                                const u16* __restrict__ Bk,
                                                const u16* __restrict__ Bv,
                                                const float* __restrict__ bq,
                                                const float* __restrict__ bk,
                                                const float* __restrict__ bv,
                                                void* __restrict__ oq,
                                                void* __restrict__ ok,
                                                void* __restrict__ ov){
  __shared__ u16 lds[6*12288];
  int y = blockIdx.y;
  const u16* A  = (y==0) ? Aq : (y==1) ? Ak : Av;
  const u16* BT = (y==0) ? Bq : (y==1) ? Bk : Bv;
  const float* bias = (y==0) ? bq : (y==1) ? bk : bv;
  void* out = (y==0) ? oq : (y==1) ? ok : ov;
  int mode = (y==2) ? 1 : 0;
  gemm_core(lds, A, BT, bias, out, mode);
}

__global__ __launch_bounds__(512) void gemm_bt(const u16* __restrict__ A,
                                               const u16* __restrict__ BT,
                                               const float* __restrict__ bias,
                                               void* __restrict__ out, int mode){
  __shared__ u16 lds[6*12288];
  gemm_core(lds, A, BT, bias, out, mode);
}

// ---------------- RMSNorm + RoPE for K -> A-fragment-linear layout ----------------
// frag (c=kv>>4, fc=f>>5) of 1KB: lane (lg=(f>>3)&3)*16+(lr=kv&15), elem j=f&7.
__global__ __launch_bounds__(256) void norm_ropeK(const u16* __restrict__ kin,
                                                  u16* __restrict__ kout,
                                                  const float* __restrict__ kwv,
                                                  const float* __restrict__ ctab,
                                                  const float* __restrict__ stab){
  int t = threadIdx.x, w = t>>6, l = t&63;
  size_t R = (size_t)blockIdx.x*4 + w;     // over B*H*S rows
  int p = (int)(R & (S_LEN-1));
  size_t base = R * HD;
  float x0 = bf2f(kin[base + l]);
  float x1 = bf2f(kin[base + 64 + l]);
  float ss = x0*x0 + x1*x1;
  #pragma unroll
  for (int m=1;m<64;m<<=1) ss += __shfl_xor(ss, m);
  float rms = sqrtf(ss * (1.0f/128.0f));
  float sc = 1.0f / (rms + 1e-6f);
  float xn0 = x0 * sc * kwv[l];
  float xn1 = x1 * sc * kwv[64+l];
  float c = ctab[(size_t)p*64 + l], s = stab[(size_t)p*64 + l];
  float o0 = xn0*c - xn1*s;
  float o1 = xn1*c + xn0*s;
  size_t plane = R >> 11;
  int kv = p & 63;
  int cci = kv >> 4, lrr = kv & 15;
  size_t tb = plane*(size_t)PLANE_ELEMS*2 + (size_t)(p>>6)*16384;
  #pragma unroll
  for (int e=0;e<2;e++){
    int f = e ? (64 + l) : l;
    float o = e ? o1 : o0;
    int fc = f >> 5, lgg = (f >> 3) & 3, jj = f & 7;
    int off = (cci*4 + fc)*1024 + (lgg*16 + lrr)*16 + jj*2;
    *(u16*)((char*)kout + tb + off) = f2bf(o);
  }
}

// ---------------- flash attention: BARRIER-FREE, zero LDS ---------------------------------
// K AND V both global->register fragment-linear (L2-resident, 1MB/plane fits XCD L2).
// 4 waves x 32 q-rows, fully independent streams. Q norm+RoPE fused in prologue.
// no-max softmax; denominator via ones-MFMA; in-lane normalize.
__global__ __launch_bounds__(256,2) void attn_fwd(const u16* __restrict__ qn, // RAW q+bias bf16 BHSF
                                                  const u16* __restrict__ knF,// K A-frag-linear
                                                  const u16* __restrict__ vt, // V B-frag-linear
                                                  const float* __restrict__ qw,
                                                  const float* __restrict__ ctab,
                                                  const float* __restrict__ stab,
                                                  u16* __restrict__ attn_out){// (B,S,H,F)
  int t = threadIdx.x, w = t>>6, l = t&63;
  int lr = l&15, lg = l>>4;

  int bid = blockIdx.x;                  // 0..511
  int xcd = bid & 7, j = bid >> 3;       // j 0..63
  int plane = xcd*4 + (j >> 4);          // 4 planes per XCD
  int qb = j & 15;
  int q0 = qb*128 + w*32;                // 32 q-rows per wave

  const s8b ones = { (short)0x3F80, (short)0x3F80, (short)0x3F80, (short)0x3F80,
                     (short)0x3F80, (short)0x3F80, (short)0x3F80, (short)0x3F80 };

  // ---- fused Q RMSNorm + RoPE + ATT_SCALE*LOG2E (once per block) ----
  s8b qf[2][4];
  {
    float qv[2][4][8], qwv[4][8];
    #pragma unroll
    for (int fc=0; fc<4; fc++)
      #pragma unroll
      for (int jj=0;jj<8;jj++) qwv[fc][jj] = qw[fc*32 + lg*8 + jj];
    #pragma unroll
    for (int qi=0; qi<2; qi++)
      #pragma unroll
      for (int fc=0; fc<4; fc++){
        s8b raw = *(const s8b*)(qn + ((size_t)plane*S_LEN + q0 + qi*16 + lr)*HD + fc*32 + lg*8);
        #pragma unroll
        for (int jj=0;jj<8;jj++) qv[qi][fc][jj] = bf2f(((const u16*)&raw)[jj]);
      }
    #pragma unroll
    for (int qi=0;qi<2;qi++){
      float ss = 0.f;
      #pragma unroll
      for (int fc=0;fc<4;fc++)
        #pragma unroll
        for (int jj=0;jj<8;jj++) ss += qv[qi][fc][jj]*qv[qi][fc][jj];
      ss += __shfl_xor(ss, 16);
      ss += __shfl_xor(ss, 32);
      float sc = (ATT_SCALE*LOG2E) / (sqrtf(ss*(1.0f/128.0f)) + 1e-6f);
      int p = q0 + qi*16 + lr;
      #pragma unroll
      for (int fc=0;fc<4;fc++){
        union { s8b v; unsigned u[4]; } pu;
        #pragma unroll
        for (int jp=0;jp<4;jp++){
          float o[2];
          #pragma unroll
          for (int e=0;e<2;e++){
            int jj = jp*2+e;
            int cc = (fc&1)*32 + lg*8 + jj;
            float cz = ctab[p*64 + cc], sz = stab[p*64 + cc];
            float xa = qv[qi][fc][jj]   * qwv[fc][jj];
            float xb = qv[qi][fc^2][jj] * qwv[fc^2][jj];
            o[e] = ((fc<2) ? (xa*cz - xb*sz) : (xa*cz + xb*sz)) * sc;
          }
          pu.u[jp] = cvtpk(o[0], o[1]);
        }
        qf[qi][fc] = pu.v;
      }
    }
  }

  f32x4 lacc[2];                         // denominators, rows q = lg*4+r (same map as oacc)
  lacc[0] = f32x4{0.f,0.f,0.f,0.f};
  lacc[1] = f32x4{0.f,0.f,0.f,0.f};
  f32x4 oacc[2][8];
  #pragma unroll
  for (int qi=0;qi<2;qi++)
    #pragma unroll
    for (int i=0;i<8;i++) oacc[qi][i] = f32x4{0.f,0.f,0.f,0.f};

  const char* kbase = (const char*)knF + (size_t)plane*PLANE_ELEMS*2;
  const char* vbase = (const char*)vt  + (size_t)plane*PLANE_ELEMS*2;

  for (int kt=0; kt<32; kt++){
    const char* kb = kbase + (size_t)kt*16384;
    const char* vb = vbase + (size_t)kt*16384;

    // V kc=0 frags issued first (land under QK^T)
    s8b vf0[8];
    #pragma unroll
    for (int fc2=0; fc2<8; fc2++)
      vf0[fc2] = *(const s8b*)(vb + fc2*1024 + l*16);

    // QK^T from register K-frags (A-frag-linear, 1KB coalesced each)
    f32x4 sacc[4][2];
    #pragma unroll
    for (int c=0;c<4;c++){
      sacc[c][0] = f32x4{0.f,0.f,0.f,0.f};
      sacc[c][1] = f32x4{0.f,0.f,0.f,0.f};
    }
    #pragma unroll
    for (int c=0;c<4;c++){
      s8b kf[4];
      #pragma unroll
      for (int fc=0; fc<4; fc++)
        kf[fc] = *(const s8b*)(kb + (c*4 + fc)*1024 + l*16);
      __builtin_amdgcn_s_setprio(1);
      #pragma unroll
      for (int fc=0; fc<4; fc++){
        sacc[c][0] = mfma16(kf[fc], qf[0][fc], sacc[c][0]);
        sacc[c][1] = mfma16(kf[fc], qf[1][fc], sacc[c][1]);
      }
      __builtin_amdgcn_s_setprio(0);
    }

    // V kc=1 frags (land under softmax)
    s8b vf1[8];
    #pragma unroll
    for (int fc2=0; fc2<8; fc2++)
      vf1[fc2] = *(const s8b*)(vb + (8+fc2)*1024 + l*16);

    float pv[2][4][4];
    #pragma unroll
    for (int qi=0;qi<2;qi++)
      #pragma unroll
      for (int c=0;c<4;c++){
        pv[qi][c][0] = exp2f(sacc[c][qi][0]);
        pv[qi][c][1] = exp2f(sacc[c][qi][1]);
        pv[qi][c][2] = exp2f(sacc[c][qi][2]);
        pv[qi][c][3] = exp2f(sacc[c][qi][3]);
      }

    s8b pa[2][2];
    #pragma unroll
    for (int qi=0;qi<2;qi++)
      #pragma unroll
      for (int kc=0;kc<2;kc++){
        union { s8b v; unsigned u[4]; } pu;
        pu.u[0] = cvtpk(pv[qi][2*kc][0],   pv[qi][2*kc][1]);
        pu.u[1] = cvtpk(pv[qi][2*kc][2],   pv[qi][2*kc][3]);
        pu.u[2] = cvtpk(pv[qi][2*kc+1][0], pv[qi][2*kc+1][1]);
        pu.u[3] = cvtpk(pv[qi][2*kc+1][2], pv[qi][2*kc+1][3]);
        pa[qi][kc] = pu.v;
      }

    __builtin_amdgcn_s_setprio(1);
    lacc[0] = mfma16(pa[0][0], ones, lacc[0]);
    lacc[1] = mfma16(pa[1][0], ones, lacc[1]);
    #pragma unroll
    for (int fc2=0; fc2<8; fc2++){
      oacc[0][fc2] = mfma16(pa[0][0], vf0[fc2], oacc[0][fc2]);
      oacc[1][fc2] = mfma16(pa[1][0], vf0[fc2], oacc[1][fc2]);
    }
    lacc[0] = mfma16(pa[0][1], ones, lacc[0]);
    lacc[1] = mfma16(pa[1][1], ones, lacc[1]);
    #pragma unroll
    for (int fc2=0; fc2<8; fc2++){
      oacc[0][fc2] = mfma16(pa[0][1], vf1[fc2], oacc[0][fc2]);
      oacc[1][fc2] = mfma16(pa[1][1], vf1[fc2], oacc[1][fc2]);
    }
    __builtin_amdgcn_s_setprio(0);
  }

  // epilogue: in-lane normalize (lacc rows == oacc rows), no shfl
  int b = plane >> 4, h = plane & 15;
  #pragma unroll
  for (int qi=0;qi<2;qi++){
    float inv[4];
    #pragma unroll
    for (int r=0;r<4;r++) inv[r] = 1.0f / lacc[qi][r];
    #pragma unroll
    for (int fc2=0; fc2<8; fc2++){
      int f = fc2*16 + lr;
      #pragma unroll
      for (int r=0;r<4;r++){
        int row = q0 + qi*16 + lg*4 + r;
        float o = oacc[qi][fc2][r] * inv[r];
        attn_out[(((size_t)b*S_LEN + row)*NHEAD + h)*HD + f] = f2bf(o);
      }
    }
  }
}

// ---------------------------------------------------------------------------
extern "C" void kernel_launch(void* const* d_in, const int* in_sizes, int n_in,
                              void* d_out, int out_size, void* d_ws, size_t ws_size,
                              hipStream_t stream){
  const float* xq = (const float*)d_in[0];
  const float* xk = (const float*)d_in[1];
  const float* xv = (const float*)d_in[2];
  const float* WQ = (const float*)d_in[3];
  const float* WK = (const float*)d_in[4];
  const float* WV = (const float*)d_in[5];
  const float* WO = (const float*)d_in[6];
  const float* bQ = (const float*)d_in[7];
  const float* bK = (const float*)d_in[8];
  const float* bV = (const float*)d_in[9];
  const float* bO = (const float*)d_in[10];
  const float* qw = (const float*)d_in[11];
  const float* kw = (const float*)d_in[12];

  char* ws = (char*)d_ws;
  size_t off = 0;
  auto alloc = [&](size_t bytes)->void*{
    void* p = ws + off; off += (bytes + 255) & ~(size_t)255; return p;
  };
  const size_t ACT = (size_t)ROWS*DM*2;    // 16.78 MB (bf16 [4096][2048])
  const size_t WMT = (size_t)DM*DM*2;      // 8.39 MB
  u16* xqb  = (u16*)alloc(ACT);
  u16* xkb  = (u16*)alloc(ACT);
  u16* xvb  = (u16*)alloc(ACT);
  u16* WqT  = (u16*)alloc(WMT);
  u16* WkT  = (u16*)alloc(WMT);
  u16* WvT  = (u16*)alloc(WMT);
  u16* WoT  = (u16*)alloc(WMT);
  u16* qraw = (u16*)alloc(ACT);
  u16* kraw = (u16*)alloc(ACT);
  u16* knF  = (u16*)alloc(ACT);
  u16* vtS  = (u16*)alloc(ACT);
  u16* attn = (u16*)alloc(ACT);
  float* ctab = (float*)alloc((size_t)S_LEN*64*4);
  float* stab = (float*)alloc((size_t)S_LEN*64*4);
  if (off > ws_size) return;               // ws too small -> absmax will flag it

  const int n4 = ROWS*DM/4;                // 2097152
  cvt4x3<<<dim3(n4/256, 3), dim3(256), 0, stream>>>((const float4*)xq, (const float4*)xk,
                                                    (const float4*)xv, (uint2*)xqb,
                                                    (uint2*)xkb, (uint2*)xvb, n4);
  rope_tab<<<dim3(S_LEN*64/256), dim3(256), 0, stream>>>(ctab, stab);
  transpose_all<<<dim3(4*4096), dim3(256), 0, stream>>>(WQ, WK, WV, WO, WqT, WkT, WvT, WoT);

  gemm_qkv<<<dim3(256,3), dim3(512), 0, stream>>>(xqb, xkb, xvb, WqT, WkT, WvT,
                                                  bQ, bK, bV, qraw, kraw, vtS);

  norm_ropeK<<<dim3(NPLANE*S_LEN/4), dim3(256), 0, stream>>>(kraw, knF, kw, ctab, stab);

  attn_fwd<<<dim3(512), dim3(256), 0, stream>>>(qraw, knF, vtS, qw, ctab, stab, attn);

  gemm_bt<<<dim3(256), dim3(512), 0, stream>>>(attn, WoT, bO, d_out, 2);
}

// Round 21
// 319.436 us; speedup vs baseline: 1.0263x; 1.0263x over previous
//
#include <hip/hip_runtime.h>
#include <stdint.h>

typedef unsigned short u16;
typedef __attribute__((ext_vector_type(8))) short  s8b;   // 8 bf16 (4 VGPRs)
typedef __attribute__((ext_vector_type(4))) float  f32x4;

#define S_LEN   2048
#define NHEAD   16
#define HD      128
#define DM      2048
#define NB      2
#define NPLANE  (NB*NHEAD)          // 32
#define ROWS    (NB*S_LEN)          // 4096 = M for all GEMMs
#define PLANE_ELEMS (S_LEN*HD)      // 262144
#define ATT_SCALE 0.08838834764831845f   // 1/sqrt(128)
#define LOG2E     1.4426950408889634f

__device__ __forceinline__ float bf2f(u16 u){
  union { unsigned u; float f; } x; x.u = ((unsigned)u) << 16; return x.f;
}
__device__ __forceinline__ u16 f2bf(float f){
  union { float f; unsigned u; } x; x.f = f;
  unsigned r = x.u + 0x7FFFu + ((x.u >> 16) & 1u);   // RNE
  return (u16)(r >> 16);
}
__device__ __forceinline__ unsigned cvtpk(float lo, float hi){
  unsigned r;
  asm("v_cvt_pk_bf16_f32 %0, %1, %2" : "=v"(r) : "v"(lo), "v"(hi));
  return r;
}

typedef const __attribute__((address_space(1))) unsigned int* gas1;
typedef __attribute__((address_space(3))) unsigned int* las3;
__device__ __forceinline__ void gload16(const void* g, void* l){
  __builtin_amdgcn_global_load_lds((gas1)g, (las3)l, 16, 0, 0);
}

__device__ __forceinline__ f32x4 mfma16(s8b a, s8b b, f32x4 c){
  return __builtin_amdgcn_mfma_f32_16x16x32_bf16(a, b, c, 0, 0, 0);
}

// ---------------- elementwise f32 -> bf16, 3 tensors in one launch ----------------
__global__ __launch_bounds__(256) void cvt4x3(const float4* __restrict__ a,
                                              const float4* __restrict__ b,
                                              const float4* __restrict__ c,
                                              uint2* __restrict__ oa,
                                              uint2* __restrict__ ob,
                                              uint2* __restrict__ oc, int n4){
  int i = blockIdx.x*256 + threadIdx.x;
  if (i >= n4) return;
  const float4* src = (blockIdx.y == 0) ? a : (blockIdx.y == 1) ? b : c;
  uint2*       dst  = (blockIdx.y == 0) ? oa : (blockIdx.y == 1) ? ob : oc;
  float4 v = src[i];
  uint2 o;
  o.x = (unsigned)f2bf(v.x) | ((unsigned)f2bf(v.y) << 16);
  o.y = (unsigned)f2bf(v.z) | ((unsigned)f2bf(v.w) << 16);
  dst[i] = o;
}

// ---------------- all 4 weight transposes in ONE launch (plain B^T layout) ----------------
__global__ __launch_bounds__(256) void transpose_all(const float* __restrict__ WQ,
                                                     const float* __restrict__ WK,
                                                     const float* __restrict__ WV,
                                                     const float* __restrict__ WO,
                                                     u16* __restrict__ WqT,
                                                     u16* __restrict__ WkT,
                                                     u16* __restrict__ WvT,
                                                     u16* __restrict__ WoT){
  __shared__ float tile[32][33];
  int u = blockIdx.x;
  int mat = u >> 12, rem = u & 4095;
  const float* in; u16* out; int R, C, outStride, z, r0, c0;
  if (mat == 0){
    in = WO; out = WoT; R = 2048; C = 2048; outStride = 2048; z = 0;
    r0 = (rem & 63)*32; c0 = (rem >> 6)*32;
  } else {
    in  = (mat == 1) ? WQ  : (mat == 2) ? WK  : WV;
    out = (mat == 1) ? WqT : (mat == 2) ? WkT : WvT;
    R = 2048; C = 128; outStride = 2048;
    z  = rem >> 8;                 // head 0..15
    r0 = (rem & 63)*32; c0 = ((rem >> 6) & 3)*32;
  }
  const float* inz = in + (size_t)z * R * C;
  u16* outz = out + (size_t)z * C * outStride;
  int tx = threadIdx.x & 31, ty = threadIdx.x >> 5;   // (32,8)
  #pragma unroll
  for (int i=0;i<4;i++)
    tile[ty*4+i][tx] = inz[(size_t)(r0+ty*4+i)*C + c0 + tx];
  __syncthreads();
  #pragma unroll
  for (int i=0;i<4;i++)
    outz[(size_t)(c0+ty*4+i)*outStride + r0 + tx] = f2bf(tile[tx][ty*4+i]);
}

// ---------------- RoPE table (f32) ----------------
__global__ __launch_bounds__(256) void rope_tab(float* __restrict__ ctab,
                                                float* __restrict__ stab){
  int i = blockIdx.x*256 + threadIdx.x;   // S_LEN*64
  int p = i >> 6, j = i & 63;
  float freq = exp2f(-(float)j * (13.287712379549449f/64.0f));  // 10000^(-j/64)
  float a = (float)p * freq;
  ctab[i] = cosf(a);
  stab[i] = sinf(a);
}

// ---------------- GEMM core (round-12 proven ring-6, counted vmcnt(9)) -------------------
// 256x128 tile, BK=64, 8 waves (4Mx2N), ring-6 half-slots (144KB), 2 phases x 16 MFMA,
// 2 barriers/K-tile, (row&7)<<4 swizzle both-sides, XCD swizzle.
// mode 0: bf16 plain (B,H,S,F) | mode 1: V fragment-linear | mode 2: f32+bias
__device__ __forceinline__ void gemm_core(u16* lds,
                                          const u16* __restrict__ A,
                                          const u16* __restrict__ BT,
                                          const float* __restrict__ bias,
                                          void* __restrict__ out, int mode){
  const int K = 2048;
  const int NT = 32;                       // K/64
  const int t = threadIdx.x, w = t >> 6, l = t & 63;
  const int lr = l & 15, lg = l >> 4;
  const int wr = w >> 1, wc = w & 1;       // 4M x 2N waves, 64x64 output each
  int bid = blockIdx.x;
  int swz = (bid & 7)*32 + (bid >> 3);     // 256 % 8 == 0, bijective
  const int M0 = (swz >> 4) * 256, N0 = (swz & 15) * 128;

  f32x4 acc[4][4];
  #pragma unroll
  for (int i=0;i<4;i++)
    #pragma unroll
    for (int j=0;j<4;j++) acc[i][j] = f32x4{0.f,0.f,0.f,0.f};

  auto stageH = [&](int ttu, int h){
    int slot = (2*ttu + h) % 6;
    int tt   = ttu & 31;
    char* base = (char*)&lds[slot*12288];
    #pragma unroll
    for (int j=0;j<2;j++){                       // A-half: 128 rows x 128B
      int d = w*2048 + j*1024 + l*16;
      int row = d >> 7;                          // 0..127
      int koff = ((l&7)*16) ^ ((row&7)<<4);
      gload16((const char*)A + ((size_t)(M0 + h*128 + row)*K + tt*64)*2 + koff,
              base + w*2048 + j*1024);
    }
    {                                            // B-half: 64 rows x 128B
      int d = w*1024 + l*16;
      int row = d >> 7;                          // 0..63
      int koff = ((l&7)*16) ^ ((row&7)<<4);
      gload16((const char*)BT + ((size_t)(N0 + h*64 + row)*K + tt*64)*2 + koff,
              base + 16384 + w*1024);
    }
  };

  stageH(0,0); stageH(0,1); stageH(1,0); stageH(1,1);

  for (int kt=0; kt<NT; kt++){
    const char* Ab = (const char*)&lds[((2*kt + (wr>>1)) % 6)*12288];
    const char* Bb = (const char*)&lds[((2*kt + wc) % 6)*12288] + 16384;

    // ---- P0: issue H(t+2,0); counted wait; barrier; af + bf(nj0,1); 16 MFMA ----
    stageH(kt+2, 0);
    asm volatile("s_waitcnt vmcnt(9)" ::: "memory");   // tile kt fully landed
    __builtin_amdgcn_s_barrier();
    __builtin_amdgcn_sched_barrier(0);

    s8b af[4][2];
    #pragma unroll
    for (int mi=0;mi<4;mi++)
      #pragma unroll
      for (int kc=0;kc<2;kc++){
        int rA = (wr&1)*64 + mi*16 + lr;
        af[mi][kc] = *(const s8b*)(Ab + rA*128 + ((kc*64 + lg*16) ^ ((rA&7)<<4)));
      }
    {
      s8b bf[2][2];
      #pragma unroll
      for (int nj=0;nj<2;nj++){
        int rB = nj*16 + lr;
        bf[nj][0] = *(const s8b*)(Bb + rB*128 + ((0*64 + lg*16) ^ ((rB&7)<<4)));
        bf[nj][1] = *(const s8b*)(Bb + rB*128 + ((1*64 + lg*16) ^ ((rB&7)<<4)));
      }
      __builtin_amdgcn_s_setprio(1);
      #pragma unroll
      for (int mi=0;mi<4;mi++)
        #pragma unroll
        for (int nj=0;nj<2;nj++){
          acc[mi][nj] = mfma16(af[mi][0], bf[nj][0], acc[mi][nj]);
          acc[mi][nj] = mfma16(af[mi][1], bf[nj][1], acc[mi][nj]);
        }
      __builtin_amdgcn_s_setprio(0);
    }
    // ---- P1: issue H(t+2,1); bf(nj2,3); 16 MFMA; end barrier ----
    stageH(kt+2, 1);
    {
      s8b bf[2][2];
      #pragma unroll
      for (int nj=0;nj<2;nj++){
        int rB = (nj+2)*16 + lr;
        bf[nj][0] = *(const s8b*)(Bb + rB*128 + ((0*64 + lg*16) ^ ((rB&7)<<4)));
        bf[nj][1] = *(const s8b*)(Bb + rB*128 + ((1*64 + lg*16) ^ ((rB&7)<<4)));
      }
      __builtin_amdgcn_s_setprio(1);
      #pragma unroll
      for (int mi=0;mi<4;mi++)
        #pragma unroll
        for (int nj=0;nj<2;nj++){
          acc[mi][nj+2] = mfma16(af[mi][0], bf[nj][0], acc[mi][nj+2]);
          acc[mi][nj+2] = mfma16(af[mi][1], bf[nj][1], acc[mi][nj+2]);
        }
      __builtin_amdgcn_s_setprio(0);
    }
    __builtin_amdgcn_sched_barrier(0);
    __builtin_amdgcn_s_barrier();
    __builtin_amdgcn_sched_barrier(0);
  }
  asm volatile("s_waitcnt vmcnt(0)" ::: "memory");   // drain wrap-stages

  // epilogue: D layout col=lane&15, row=(lane>>4)*4+reg
  #pragma unroll
  for (int mi=0;mi<4;mi++){
    int growb = M0 + wr*64 + mi*16 + lg*4;
    #pragma unroll
    for (int nj=0;nj<4;nj++){
      int gcol = N0 + wc*64 + nj*16 + lr;
      float bv = bias[gcol];
      #pragma unroll
      for (int r=0;r<4;r++){
        int grow = growb + r;
        float v = acc[mi][nj][r] + bv;
        if (mode == 2){
          ((float*)out)[(size_t)grow*2048 + gcol] = v;
        } else {
          int b = grow >> 11, p = grow & 2047;
          int h = gcol >> 7,  f = gcol & 127;
          if (mode == 0){
            ((u16*)out)[(((size_t)(b*NHEAD+h))*S_LEN + p)*HD + f] = f2bf(v);
          } else {
            // V fragment-linear: 16 frags x 1KB per kv-tile; sigma-permute folded in.
            size_t base = ((size_t)(b*NHEAD+h)*PLANE_ELEMS)*2 + (size_t)(p>>6)*16384;
            int p6 = p & 63;
            int q_ = ((p6&12)<<1) | (p6&3) | ((p6&16)>>2);
            int kvp = (p6 & 32) | q_;
            int kc = kvp >> 5, lgv = (kvp >> 3) & 3, jv = kvp & 7;
            int off = (kc*8 + (f>>4))*1024 + (lgv*16 + (f&15))*16 + jv*2;
            *(u16*)((char*)out + base + off) = f2bf(v);
          }
        }
      }
    }
  }
}

// merged QKV launch: blockIdx.y selects {q,k,v}
__global__ __launch_bounds__(512) void gemm_qkv(const u16* __restrict__ Aq,
                                                const u16* __restrict__ Ak,
                                                const u16* __restrict__ Av,
                                                const u16* __restrict__ Bq,
                                                const u16* __restrict__ Bk,
                                                const u16* __restrict__ Bv,
                                                const float* __restrict__ bq,
                                                const float* __restrict__ bk,
                                                const float* __restrict__ bv,
                                                void* __restrict__ oq,
                                                void* __restrict__ ok,
                                                void* __restrict__ ov){
  __shared__ u16 lds[6*12288];
  int y = blockIdx.y;
  const u16* A  = (y==0) ? Aq : (y==1) ? Ak : Av;
  const u16* BT = (y==0) ? Bq : (y==1) ? Bk : Bv;
  const float* bias = (y==0) ? bq : (y==1) ? bk : bv;
  void* out = (y==0) ? oq : (y==1) ? ok : ov;
  int mode = (y==2) ? 1 : 0;
  gemm_core(lds, A, BT, bias, out, mode);
}

__global__ __launch_bounds__(512) void gemm_bt(const u16* __restrict__ A,
                                               const u16* __restrict__ BT,
                                               const float* __restrict__ bias,
                                               void* __restrict__ out, int mode){
  __shared__ u16 lds[6*12288];
  gemm_core(lds, A, BT, bias, out, mode);
}

// ---------------- RMSNorm + RoPE for K only (writes swizzled knT layout) ----------------
__global__ __launch_bounds__(256) void norm_ropeK(const u16* __restrict__ kin,
                                                  u16* __restrict__ kout,
                                                  const float* __restrict__ kwv,
                                                  const float* __restrict__ ctab,
                                                  const float* __restrict__ stab){
  int t = threadIdx.x, w = t>>6, l = t&63;
  size_t R = (size_t)blockIdx.x*4 + w;     // over B*H*S rows
  int p = (int)(R & (S_LEN-1));
  size_t base = R * HD;
  float x0 = bf2f(kin[base + l]);
  float x1 = bf2f(kin[base + 64 + l]);
  float ss = x0*x0 + x1*x1;
  #pragma unroll
  for (int m=1;m<64;m<<=1) ss += __shfl_xor(ss, m);
  float rms = sqrtf(ss * (1.0f/128.0f));
  float sc = 1.0f / (rms + 1e-6f);
  float xn0 = x0 * sc * kwv[l];
  float xn1 = x1 * sc * kwv[64+l];
  float c = ctab[(size_t)p*64 + l], s = stab[(size_t)p*64 + l];
  float o0 = xn0*c - xn1*s;
  float o1 = xn1*c + xn0*s;
  size_t plane = R >> 11;
  int kv = p & 63;
  size_t tb = (plane*(size_t)PLANE_ELEMS + (size_t)(p>>6)*8192) * 2;
  int b0 = (kv*256 + l*2)        ^ ((kv&7)<<4);
  int b1 = (kv*256 + (64+l)*2)   ^ ((kv&7)<<4);
  *(u16*)((char*)kout + tb + b0) = f2bf(o0);
  *(u16*)((char*)kout + tb + b1) = f2bf(o1);
}

// ---------------- flash attention: 4 waves, QBLK=128 (32 rows/wave) ----------------------
// Q norm+RoPE+scale fused into the load prologue (each lane owns complete q-rows;
// RoPE pair f^64 = fc^2 in-lane). K LDS dbuf; V global->register; no-max softmax;
// denominator via ones-MFMA; in-lane normalize.
__global__ __launch_bounds__(256,2) void attn_fwd(const u16* __restrict__ qn, // RAW q+bias bf16 BHSF
                                                  const u16* __restrict__ kn, // tiled swizzled
                                                  const u16* __restrict__ vt, // V fragment-linear
                                                  const float* __restrict__ qw,
                                                  const float* __restrict__ ctab,
                                                  const float* __restrict__ stab,
                                                  u16* __restrict__ attn_out){// (B,S,H,F)
  __shared__ u16 Klds[2][8192];     // [64 kv][128 f] swizzled
  int t = threadIdx.x, w = t>>6, l = t&63;
  int lr = l&15, lg = l>>4;

  int bid = blockIdx.x;                  // 0..511
  int xcd = bid & 7, j = bid >> 3;       // j 0..63
  int plane = xcd*4 + (j >> 4);          // 4 planes per XCD
  int qb = j & 15;
  int q0 = qb*128 + w*32;                // 32 q-rows per wave

  const s8b ones = { (short)0x3F80, (short)0x3F80, (short)0x3F80, (short)0x3F80,
                     (short)0x3F80, (short)0x3F80, (short)0x3F80, (short)0x3F80 };

  // ---- fused Q RMSNorm + RoPE + ATT_SCALE*LOG2E (once per block) ----
  s8b qf[2][4];
  {
    float qv[2][4][8], qwv[4][8];
    #pragma unroll
    for (int fc=0; fc<4; fc++)
      #pragma unroll
      for (int jj=0;jj<8;jj++) qwv[fc][jj] = qw[fc*32 + lg*8 + jj];
    #pragma unroll
    for (int qi=0; qi<2; qi++)
      #pragma unroll
      for (int fc=0; fc<4; fc++){
        s8b raw = *(const s8b*)(qn + ((size_t)plane*S_LEN + q0 + qi*16 + lr)*HD + fc*32 + lg*8);
        #pragma unroll
        for (int jj=0;jj<8;jj++) qv[qi][fc][jj] = bf2f(((const u16*)&raw)[jj]);
      }
    #pragma unroll
    for (int qi=0;qi<2;qi++){
      float ss = 0.f;
      #pragma unroll
      for (int fc=0;fc<4;fc++)
        #pragma unroll
        for (int jj=0;jj<8;jj++) ss += qv[qi][fc][jj]*qv[qi][fc][jj];
      ss += __shfl_xor(ss, 16);
      ss += __shfl_xor(ss, 32);
      float sc = (ATT_SCALE*LOG2E) / (sqrtf(ss*(1.0f/128.0f)) + 1e-6f);
      int p = q0 + qi*16 + lr;
      #pragma unroll
      for (int fc=0;fc<4;fc++){
        union { s8b v; unsigned u[4]; } pu;
        #pragma unroll
        for (int jp=0;jp<4;jp++){
          float o[2];
          #pragma unroll
          for (int e=0;e<2;e++){
            int jj = jp*2+e;
            int cc = (fc&1)*32 + lg*8 + jj;
            float cz = ctab[p*64 + cc], sz = stab[p*64 + cc];
            float xa = qv[qi][fc][jj]   * qwv[fc][jj];
            float xb = qv[qi][fc^2][jj] * qwv[fc^2][jj];
            o[e] = ((fc<2) ? (xa*cz - xb*sz) : (xa*cz + xb*sz)) * sc;
          }
          pu.u[jp] = cvtpk(o[0], o[1]);
        }
        qf[qi][fc] = pu.v;
      }
    }
  }

  f32x4 lacc[2];                         // denominators, rows q = lg*4+r (same map as oacc)
  lacc[0] = f32x4{0.f,0.f,0.f,0.f};
  lacc[1] = f32x4{0.f,0.f,0.f,0.f};
  f32x4 oacc[2][8];
  #pragma unroll
  for (int qi=0;qi<2;qi++)
    #pragma unroll
    for (int i=0;i<8;i++) oacc[qi][i] = f32x4{0.f,0.f,0.f,0.f};

  const u16* kbase = kn + (size_t)plane*PLANE_ELEMS;
  const char* vbase = (const char*)vt + (size_t)plane*PLANE_ELEMS*2;

  auto stage = [&](int buf, int kt){     // K only: 4 gloads/wave
    #pragma unroll
    for (int i=0;i<4;i++)
      gload16(kbase + (size_t)kt*8192 + w*2048 + i*512 + l*8, &Klds[buf][w*2048 + i*512]);
  };

  stage(0, 0);
  int cur = 0;
  for (int kt=0; kt<32; kt++){
    __syncthreads();                     // Klds[cur] staged; prior reads done
    if (kt+1 < 32) stage(cur^1, kt+1);

    const char* vb = vbase + (size_t)kt*16384;
    s8b vf0[8];
    #pragma unroll
    for (int fc2=0; fc2<8; fc2++)
      vf0[fc2] = *(const s8b*)(vb + fc2*1024 + l*16);

    f32x4 sacc[4][2];
    #pragma unroll
    for (int c=0;c<4;c++){
      sacc[c][0] = f32x4{0.f,0.f,0.f,0.f};
      sacc[c][1] = f32x4{0.f,0.f,0.f,0.f};
    }
    __builtin_amdgcn_s_setprio(1);
    #pragma unroll
    for (int c=0;c<4;c++){
      int kv = c*16 + lr;
      #pragma unroll
      for (int fc=0; fc<4; fc++){
        int byte = (kv*256 + (fc*32 + lg*8)*2) ^ ((kv&7)<<4);
        s8b kf = *(const s8b*)((const char*)&Klds[cur][0] + byte);
        sacc[c][0] = mfma16(kf, qf[0][fc], sacc[c][0]);
        sacc[c][1] = mfma16(kf, qf[1][fc], sacc[c][1]);
      }
    }
    __builtin_amdgcn_s_setprio(0);

    s8b vf1[8];
    #pragma unroll
    for (int fc2=0; fc2<8; fc2++)
      vf1[fc2] = *(const s8b*)(vb + (8+fc2)*1024 + l*16);

    float pv[2][4][4];
    #pragma unroll
    for (int qi=0;qi<2;qi++)
      #pragma unroll
      for (int c=0;c<4;c++){
        pv[qi][c][0] = exp2f(sacc[c][qi][0]);
        pv[qi][c][1] = exp2f(sacc[c][qi][1]);
        pv[qi][c][2] = exp2f(sacc[c][qi][2]);
        pv[qi][c][3] = exp2f(sacc[c][qi][3]);
      }

    s8b pa[2][2];
    #pragma unroll
    for (int qi=0;qi<2;qi++)
      #pragma unroll
      for (int kc=0;kc<2;kc++){
        union { s8b v; unsigned u[4]; } pu;
        pu.u[0] = cvtpk(pv[qi][2*kc][0],   pv[qi][2*kc][1]);
        pu.u[1] = cvtpk(pv[qi][2*kc][2],   pv[qi][2*kc][3]);
        pu.u[2] = cvtpk(pv[qi][2*kc+1][0], pv[qi][2*kc+1][1]);
        pu.u[3] = cvtpk(pv[qi][2*kc+1][2], pv[qi][2*kc+1][3]);
        pa[qi][kc] = pu.v;
      }

    __builtin_amdgcn_s_setprio(1);
    lacc[0] = mfma16(pa[0][0], ones, lacc[0]);
    lacc[1] = mfma16(pa[1][0], ones, lacc[1]);
    #pragma unroll
    for (int fc2=0; fc2<8; fc2++){
      oacc[0][fc2] = mfma16(pa[0][0], vf0[fc2], oacc[0][fc2]);
      oacc[1][fc2] = mfma16(pa[1][0], vf0[fc2], oacc[1][fc2]);
    }
    lacc[0] = mfma16(pa[0][1], ones, lacc[0]);
    lacc[1] = mfma16(pa[1][1], ones, lacc[1]);
    #pragma unroll
    for (int fc2=0; fc2<8; fc2++){
      oacc[0][fc2] = mfma16(pa[0][1], vf1[fc2], oacc[0][fc2]);
      oacc[1][fc2] = mfma16(pa[1][1], vf1[fc2], oacc[1][fc2]);
    }
    __builtin_amdgcn_s_setprio(0);
    cur ^= 1;
  }

  // epilogue: in-lane normalize (lacc rows == oacc rows), no shfl
  int b = plane >> 4, h = plane & 15;
  #pragma unroll
  for (int qi=0;qi<2;qi++){
    float inv[4];
    #pragma unroll
    for (int r=0;r<4;r++) inv[r] = 1.0f / lacc[qi][r];
    #pragma unroll
    for (int fc2=0; fc2<8; fc2++){
      int f = fc2*16 + lr;
      #pragma unroll
      for (int r=0;r<4;r++){
        int row = q0 + qi*16 + lg*4 + r;
        float o = oacc[qi][fc2][r] * inv[r];
        attn_out[(((size_t)b*S_LEN + row)*NHEAD + h)*HD + f] = f2bf(o);
      }
    }
  }
}

// ---------------------------------------------------------------------------
extern "C" void kernel_launch(void* const* d_in, const int* in_sizes, int n_in,
                              void* d_out, int out_size, void* d_ws, size_t ws_size,
                              hipStream_t stream){
  const float* xq = (const float*)d_in[0];
  const float* xk = (const float*)d_in[1];
  const float* xv = (const float*)d_in[2];
  const float* WQ = (const float*)d_in[3];
  const float* WK = (const float*)d_in[4];
  const float* WV = (const float*)d_in[5];
  const float* WO = (const float*)d_in[6];
  const float* bQ = (const float*)d_in[7];
  const float* bK = (const float*)d_in[8];
  const float* bV = (const float*)d_in[9];
  const float* bO = (const float*)d_in[10];
  const float* qw = (const float*)d_in[11];
  const float* kw = (const float*)d_in[12];

  char* ws = (char*)d_ws;
  size_t off = 0;
  auto alloc = [&](size_t bytes)->void*{
    void* p = ws + off; off += (bytes + 255) & ~(size_t)255; return p;
  };
  const size_t ACT = (size_t)ROWS*DM*2;    // 16.78 MB (bf16 [4096][2048])
  const size_t WMT = (size_t)DM*DM*2;      // 8.39 MB
  u16* xqb  = (u16*)alloc(ACT);
  u16* xkb  = (u16*)alloc(ACT);
  u16* xvb  = (u16*)alloc(ACT);
  u16* WqT  = (u16*)alloc(WMT);
  u16* WkT  = (u16*)alloc(WMT);
  u16* WvT  = (u16*)alloc(WMT);
  u16* WoT  = (u16*)alloc(WMT);
  u16* qraw = (u16*)alloc(ACT);
  u16* kraw = (u16*)alloc(ACT);
  u16* knT  = (u16*)alloc(ACT);
  u16* vtS  = (u16*)alloc(ACT);
  u16* attn = (u16*)alloc(ACT);
  float* ctab = (float*)alloc((size_t)S_LEN*64*4);
  float* stab = (float*)alloc((size_t)S_LEN*64*4);
  if (off > ws_size) return;               // ws too small -> absmax will flag it

  const int n4 = ROWS*DM/4;                // 2097152
  cvt4x3<<<dim3(n4/256, 3), dim3(256), 0, stream>>>((const float4*)xq, (const float4*)xk,
                                                    (const float4*)xv, (uint2*)xqb,
                                                    (uint2*)xkb, (uint2*)xvb, n4);
  rope_tab<<<dim3(S_LEN*64/256), dim3(256), 0, stream>>>(ctab, stab);
  transpose_all<<<dim3(4*4096), dim3(256), 0, stream>>>(WQ, WK, WV, WO, WqT, WkT, WvT, WoT);

  gemm_qkv<<<dim3(256,3), dim3(512), 0, stream>>>(xqb, xkb, xvb, WqT, WkT, WvT,
                                                  bQ, bK, bV, qraw, kraw, vtS);

  norm_ropeK<<<dim3(NPLANE*S_LEN/4), dim3(256), 0, stream>>>(kraw, knT, kw, ctab, stab);

  attn_fwd<<<dim3(512), dim3(256), 0, stream>>>(qraw, knT, vtS, qw, ctab, stab, attn);

  gemm_bt<<<dim3(256), dim3(512), 0, stream>>>(attn, WoT, bO, d_out, 2);
}